// Round 9
// baseline (259.043 us; speedup 1.0000x reference)
//
#include <hip/hip_runtime.h>
#include <math.h>

#define B_  32
#define S_  1024
#define D_  256
#define H_  8
#define DK_ 32
#define MASKV (-1e-30f)
#define LOG2E 1.44269504f

typedef __attribute__((ext_vector_type(4))) short bf4_t;   // 4 bf16 (2 VGPRs)
typedef __attribute__((ext_vector_type(8))) short bf8_t;   // 8 bf16 (4 VGPRs)
typedef __attribute__((ext_vector_type(4))) float f4_t;    // MFMA accumulator

__device__ __forceinline__ unsigned fbits(float x) {
    union { float f; unsigned u; } v; v.f = x; return v.u;
}
__device__ __forceinline__ float bitsf(unsigned u) {
    union { unsigned u; float f; } v; v.u = u; return v.f;
}

#if __has_builtin(__builtin_amdgcn_exp2f)
#define EXP2F(x) __builtin_amdgcn_exp2f(x)
#else
#define EXP2F(x) __expf((x) * 0.69314718f)
#endif

// v_perm selector: D = [S1.hi16 (low half), S0.hi16 (high half)]
#define PSEL 0x07060302u

#define MFMA16 __builtin_amdgcn_mfma_f32_16x16x16bf16_1k
#define MFMA32 __builtin_amdgcn_mfma_f32_16x16x32_bf16

// ===========================================================================
// FRAG-PACKED LAYOUTS (lane-linear, wave-contiguous):
//  W   (per a): off = a*65536 + ((kc*16 + ng)*64 + lane)*8 + j
//  Q/K (per bh): off = ((bh*64 + grp)*64 + lane)*8 + j
//  V   (per bh): off = bh*32768 + (((kt*4 + ks)*2 + p)*256) + lane*4 + j
//      holds V[dv = p*16 + (lane&15)][key = kt*64 + ks*16 + (lane>>4)*4 + j]
//  Every MFMA fragment load = 64 lanes x 8-16B contiguous.
// ===========================================================================

// ---------------------------------------------------------------------------
// prep_w: W[h][d][k] fp32 -> frag-packed hi/lo bf16.  (byte-identical to r8)
// ---------------------------------------------------------------------------
__global__ __launch_bounds__(256) void prep_w(
    const float* __restrict__ Wq, const float* __restrict__ Wk,
    const float* __restrict__ Wv, short* __restrict__ WpH, short* __restrict__ WpL)
{
    const int a = blockIdx.x >> 3;
    const int h = blockIdx.x & 7;
    const float* W = (a == 0 ? Wq : (a == 1 ? Wk : Wv)) + (size_t)h * 256 * 32;
    const int t = threadIdx.x;
    const int k    = t & 31;
    const int dgrp = t >> 5;
    const int ng   = h * 2 + (k >> 4);
    const int l15  = k & 15;
#pragma unroll
    for (int jj = blockIdx.y * 2; jj < blockIdx.y * 2 + 2; ++jj) {
        const int d0 = jj * 32 + dgrp * 4;
        float x[4];
#pragma unroll
        for (int r = 0; r < 4; ++r) x[r] = W[(size_t)(d0 + r) * 32 + k];
        unsigned hu[4], lu[4];
#pragma unroll
        for (int r = 0; r < 4; ++r) {
            unsigned hb = (fbits(x[r]) + 0x8000u) & 0xFFFF0000u;
            hu[r] = hb;
            lu[r] = fbits(x[r] - bitsf(hb)) + 0x8000u;
        }
        uint2 hp = make_uint2(__builtin_amdgcn_perm(hu[1], hu[0], PSEL),
                              __builtin_amdgcn_perm(hu[3], hu[2], PSEL));
        uint2 lp = make_uint2(__builtin_amdgcn_perm(lu[1], lu[0], PSEL),
                              __builtin_amdgcn_perm(lu[3], lu[2], PSEL));
        const int quad = (d0 >> 3) & 3;
        const int jb   = d0 & 7;
        size_t off = (size_t)a * 65536
                   + ((size_t)(jj * 16 + ng) * 64 + quad * 16 + l15) * 8 + jb;
        *(uint2*)&WpH[off] = hp;
        *(uint2*)&WpL[off] = lp;
    }
}

// ---------------------------------------------------------------------------
// proj: C[32768,256] = X * Wt^T via split-bf16 MFMA.  (byte-identical to r8)
// ---------------------------------------------------------------------------
__global__ __launch_bounds__(256) void proj_kernel(
    const float* __restrict__ Xq, const float* __restrict__ Xk,
    const float* __restrict__ Xv, const float* __restrict__ mask,
    const short* __restrict__ WpH, const short* __restrict__ WpL,
    short* __restrict__ qpH, short* __restrict__ qpL,
    short* __restrict__ kpH, short* __restrict__ kpL,
    short* __restrict__ vpF)
{
    __shared__ __align__(16) short XsH[8192];   // 4 kc x 4 t x 64 lanes x 8
    __shared__ __align__(16) short XsL[8192];

    const int a  = blockIdx.y;
    const float* X = (a == 0 ? Xq : (a == 1 ? Xk : Xv));
    const short* WH = WpH + (size_t)a * 65536;
    const short* WL = WpL + (size_t)a * 65536;
    const int m0 = blockIdx.x * 64;

    const int tid  = threadIdx.x;
    const int lane = tid & 63;
    const int wv   = tid >> 6;
    const int l15  = lane & 15;
    const int quad = lane >> 4;

    f4_t acc[4][4];
#pragma unroll
    for (int i = 0; i < 4; ++i)
#pragma unroll
        for (int j = 0; j < 4; ++j) acc[i][j] = (f4_t){0.f, 0.f, 0.f, 0.f};

    const int r    = tid >> 2;               // row 0..63
    const int dseg = tid & 3;                // local kc
    const int tix  = r >> 4;
    const int rl15 = r & 15;

    // per-wave W fragment base (shorts); per-(kc,ns) offsets are constants
    const short* WHb = WH + (wv * 4) * 512 + lane * 8;
    const short* WLb = WL + (wv * 4) * 512 + lane * 8;

    bf8_t wAh[4], wAl[4], wBh[4], wBl[4];

#define WLOAD(BUFh, BUFl, KC)                                                  \
    _Pragma("unroll")                                                          \
    for (int ns = 0; ns < 4; ++ns) {                                           \
        BUFh[ns] = *(const bf8_t*)&WHb[(KC) * 8192 + ns * 512];                \
        BUFl[ns] = *(const bf8_t*)&WLb[(KC) * 8192 + ns * 512];                \
    }

#define STAGE_X(H2)                                                            \
    {                                                                          \
        const float* xp = X + (size_t)(m0 + r) * 256 + (H2) * 128 + dseg * 32; \
        _Pragma("unroll")                                                      \
        for (int q = 0; q < 4; ++q) {                                          \
            float4 x0 = *(const float4*)(xp + q * 8);                          \
            float4 x1 = *(const float4*)(xp + q * 8 + 4);                      \
            float xv[8] = {x0.x, x0.y, x0.z, x0.w, x1.x, x1.y, x1.z, x1.w};    \
            bf8_t hi, lo;                                                      \
            _Pragma("unroll")                                                  \
            for (int j = 0; j < 8; ++j) {                                      \
                unsigned hu = (fbits(xv[j]) + 0x8000u) & 0xFFFF0000u;          \
                hi[j] = (short)(hu >> 16);                                     \
                lo[j] = (short)((fbits(xv[j] - bitsf(hu)) + 0x8000u) >> 16);   \
            }                                                                  \
            const int off = ((dseg * 4 + tix) * 64 + q * 16 + rl15) * 8;       \
            *(bf8_t*)&XsH[off] = hi;                                           \
            *(bf8_t*)&XsL[off] = lo;                                           \
        }                                                                      \
    }

#define COMPUTE(KCL, BUFh, BUFl)                                               \
    {                                                                          \
        bf8_t xH[4], xL[4];                                                    \
        _Pragma("unroll")                                                      \
        for (int t = 0; t < 4; ++t) {                                          \
            xH[t] = *(const bf8_t*)&XsH[(((KCL) * 4 + t) * 64 + lane) * 8];    \
            xL[t] = *(const bf8_t*)&XsL[(((KCL) * 4 + t) * 64 + lane) * 8];    \
        }                                                                      \
        _Pragma("unroll")                                                      \
        for (int ns = 0; ns < 4; ++ns) {                                       \
            _Pragma("unroll")                                                  \
            for (int t = 0; t < 4; ++t) {                                      \
                f4_t c = acc[t][ns];                                           \
                if (a < 2) {                                                   \
                    c = MFMA32(BUFh[ns], xH[t], c, 0, 0, 0);                   \
                    c = MFMA32(BUFl[ns], xH[t], c, 0, 0, 0);                   \
                    c = MFMA32(BUFh[ns], xL[t], c, 0, 0, 0);                   \
                } else {                                                       \
                    c = MFMA32(xH[t], BUFh[ns], c, 0, 0, 0);                   \
                    c = MFMA32(xH[t], BUFl[ns], c, 0, 0, 0);                   \
                    c = MFMA32(xL[t], BUFh[ns], c, 0, 0, 0);                   \
                }                                                              \
                acc[t][ns] = c;                                                \
            }                                                                  \
        }                                                                      \
    }

    WLOAD(wAh, wAl, 0)                 // kc0 W in flight during X staging
    STAGE_X(0)
    __syncthreads();

    WLOAD(wBh, wBl, 1)  COMPUTE(0, wAh, wAl)
    WLOAD(wAh, wAl, 2)  COMPUTE(1, wBh, wBl)
    WLOAD(wBh, wBl, 3)  COMPUTE(2, wAh, wAl)
    WLOAD(wAh, wAl, 4)  COMPUTE(3, wBh, wBl)

    __syncthreads();                   // half-0 LDS reads done
    STAGE_X(1)
    __syncthreads();

    WLOAD(wBh, wBl, 5)  COMPUTE(0, wAh, wAl)
    WLOAD(wAh, wAl, 6)  COMPUTE(1, wBh, wBl)
    WLOAD(wBh, wBl, 7)  COMPUTE(2, wAh, wAl)
                        COMPUTE(3, wBh, wBl)

#undef WLOAD
#undef STAGE_X
#undef COMPUTE

    // ---- epilogue ----
    const int b  = m0 >> 10;
    const int sB = m0 & 1023;
    if (a < 2) {
        short* dH = (a == 0) ? qpH : kpH;
        short* dL = (a == 0) ? qpL : kpL;
        const float* mbp = mask + (size_t)b * 1024;
#pragma unroll
        for (int t = 0; t < 4; ++t) {
            const int s = sB + t * 16 + l15;
            const float scale = (a == 0) ? LOG2E : mbp[s];
            const int grp = (sB >> 4) + t;
#pragma unroll
            for (int ns = 0; ns < 4; ++ns) {
                const int h_    = wv * 2 + (ns >> 1);
                const int quadA = (ns & 1) * 2 + (quad >> 1);
                const int jb    = (quad & 1) * 4;
                unsigned hu[4], lu[4];
#pragma unroll
                for (int rr = 0; rr < 4; ++rr) {
                    float x = acc[t][ns][rr] * scale;
                    unsigned h32 = fbits(x) + 0x8000u;
                    hu[rr] = h32;
                    float hf = bitsf(h32 & 0xFFFF0000u);
                    lu[rr] = fbits(x - hf) + 0x8000u;
                }
                uint2 hp = make_uint2(__builtin_amdgcn_perm(hu[1], hu[0], PSEL),
                                      __builtin_amdgcn_perm(hu[3], hu[2], PSEL));
                uint2 lp = make_uint2(__builtin_amdgcn_perm(lu[1], lu[0], PSEL),
                                      __builtin_amdgcn_perm(lu[3], lu[2], PSEL));
                size_t off = (((size_t)(b * 8 + h_) * 64 + grp) * 64
                              + quadA * 16 + l15) * 8 + jb;
                *(uint2*)&dH[off] = hp;
                *(uint2*)&dL[off] = lp;
            }
        }
    } else {
        // V epilogue -> frag-packed vpF.
        const int kt = sB >> 6;
#pragma unroll
        for (int t = 0; t < 4; ++t) {
#pragma unroll
            for (int ns = 0; ns < 4; ++ns) {
                const int p  = ns & 1;
                const int h_ = wv * 2 + (ns >> 1);
                const int bh = b * 8 + h_;
                unsigned eu[4];
#pragma unroll
                for (int rr = 0; rr < 4; ++rr) eu[rr] = fbits(acc[t][ns][rr]) + 0x8000u;
                uint2 pk = make_uint2(__builtin_amdgcn_perm(eu[1], eu[0], PSEL),
                                      __builtin_amdgcn_perm(eu[3], eu[2], PSEL));
                size_t off = ((((size_t)bh * 16 + kt) * 4 + t) * 2 + p) * 256
                           + (quad * 16 + l15) * 4;
                *(uint2*)&vpF[off] = pk;
            }
        }
    }
}

// ---------------------------------------------------------------------------
// attn: LDS-free, barrier-free (r8 memory path) + DEFERRED-EXP PIPELINE:
// tile kt keeps its f32 scores in sc[2][4]; during tile kt+1 the exp/pack
// of tile kt is issued INTERLEAVED BETWEEN the QK MFMAs of kt+1 (no data
// dependency), so within one wave the trans/VALU pipe fills the MFMA
// throughput gaps. r8 evidence: dur == MFMA-time + VALU-time (MfmaUtil 49
// + VALUBusy 48, no overlap) because exp(kt) depended on QK(kt) just
// issued; this removes that dependency. PV(kt-1) runs right after its pf
// is produced -- accumulation order identical to r8 (absmax must match).
// ---------------------------------------------------------------------------
__global__ __launch_bounds__(256) void attn_kernel(
    const short* __restrict__ qpH, const short* __restrict__ qpL,
    const short* __restrict__ kpH, const short* __restrict__ kpL,
    const short* __restrict__ vpF, float* __restrict__ out)
{
    const int tid  = threadIdx.x;
    const int lane = tid & 63;
    const int wv   = tid >> 6;
    const int l15  = lane & 15;
    const int quad = lane >> 4;

    // launch-linear id -> XCD-contiguous (bh, qt) assignment
    const int L  = (blockIdx.z * gridDim.y + blockIdx.y) * gridDim.x + blockIdx.x;
    const int li = L >> 3;
    const int bh = (L & 7) * 32 + (li >> 3);
    const int qt = li & 7;
    const int b  = bh >> 3;
    const int h  = bh & 7;
    const int woff = qt * 128 + wv * 32;

    bf8_t qh[2], ql[2];
#pragma unroll
    for (int qs = 0; qs < 2; ++qs) {
        const int grp = qt * 8 + wv * 2 + qs;      // (woff + qs*16) >> 4
        size_t off = (((size_t)bh * 64 + grp) * 64 + lane) * 8;
        qh[qs] = *(const bf8_t*)&qpH[off];
        ql[qs] = *(const bf8_t*)&qpL[off];
    }

    f4_t accO[2][2];
    f4_t accS[2];
#pragma unroll
    for (int i = 0; i < 2; ++i) {
        accS[i] = (f4_t){0.f, 0.f, 0.f, 0.f};
#pragma unroll
        for (int j = 0; j < 2; ++j) accO[i][j] = (f4_t){0.f, 0.f, 0.f, 0.f};
    }
    const bf4_t ones4 = {(short)0x3F80, (short)0x3F80, (short)0x3F80, (short)0x3F80};

    // walking base pointers (shorts)
    const short* kHp = kpH + (size_t)bh * 64 * 512 + lane * 8;   // K tile kt
    const short* kLp = kpL + (size_t)bh * 64 * 512 + lane * 8;
    const short* vFp = vpF + (size_t)bh * 32768 + lane * 4;      // V tile (lags 1)

    bf8_t kAh[4], kAl[4], kBh[4], kBl[4];
    bf4_t vR[8];
    f4_t  sc[2][4];        // f32 scores of the PREVIOUS tile (deferred exp)

// one k-tile. KCUR*: K regs for this tile. KNXT*: dest for next tile's K
// (kHp/kLp point there). DO_SM: exp/pack+PV for the PREVIOUS tile, whose
// scores sit in sc[][] and whose V tile vFp points at. The exp ops are
// textually interleaved between this tile's QK MFMAs (independent -> the
// wave issues them while the MFMA pipe drains). sc[qs][ks] is read for exp
// BEFORE being overwritten with this tile's scores (WAR via renaming).
#define TILE(DO_KLOAD, DO_SM, KCURh, KCURl, KNXTh, KNXTl)                       \
    {                                                                           \
        if (DO_KLOAD) {                                                         \
            _Pragma("unroll")                                                   \
            for (int ks = 0; ks < 4; ++ks) {                                    \
                KNXTh[ks] = *(const bf8_t*)&kHp[ks * 512];                      \
                KNXTl[ks] = *(const bf8_t*)&kLp[ks * 512];                      \
            }                                                                   \
        }                                                                       \
        if (DO_SM) {                                                            \
            _Pragma("unroll")                                                   \
            for (int ks = 0; ks < 4; ++ks) {                                    \
                vR[ks * 2]     = *(const bf4_t*)&vFp[(ks * 2) * 256];           \
                vR[ks * 2 + 1] = *(const bf4_t*)&vFp[(ks * 2 + 1) * 256];       \
            }                                                                   \
        }                                                                       \
        __builtin_amdgcn_s_setprio(1);                                          \
        _Pragma("unroll")                                                       \
        for (int ks = 0; ks < 4; ++ks) {                                        \
            f4_t c0 = MFMA32(KCURh[ks], qh[0], (f4_t){0.f, 0.f, 0.f, 0.f}, 0, 0, 0); \
            f4_t c1 = MFMA32(KCURh[ks], qh[1], (f4_t){0.f, 0.f, 0.f, 0.f}, 0, 0, 0); \
            unsigned e0[4], e1[4];                                              \
            if (DO_SM) {                                                        \
                _Pragma("unroll")                                               \
                for (int r = 0; r < 4; ++r) e0[r] = fbits(EXP2F(sc[0][ks][r])); \
            }                                                                   \
            c0 = MFMA32(KCURl[ks], qh[0], c0, 0, 0, 0);                         \
            c1 = MFMA32(KCURl[ks], qh[1], c1, 0, 0, 0);                         \
            if (DO_SM) {                                                        \
                _Pragma("unroll")                                               \
                for (int r = 0; r < 4; ++r) e1[r] = fbits(EXP2F(sc[1][ks][r])); \
            }                                                                   \
            c0 = MFMA32(KCURh[ks], ql[0], c0, 0, 0, 0);                         \
            c1 = MFMA32(KCURh[ks], ql[1], c1, 0, 0, 0);                         \
            if (DO_SM) {                                                        \
                union { uint2 u; bf4_t v; } cv0, cv1;                           \
                cv0.u = make_uint2(__builtin_amdgcn_perm(e0[1], e0[0], PSEL),   \
                                   __builtin_amdgcn_perm(e0[3], e0[2], PSEL));  \
                cv1.u = make_uint2(__builtin_amdgcn_perm(e1[1], e1[0], PSEL),   \
                                   __builtin_amdgcn_perm(e1[3], e1[2], PSEL));  \
                bf4_t pf0 = cv0.v, pf1 = cv1.v;                                 \
                accO[0][0] = MFMA16(vR[ks * 2],     pf0, accO[0][0], 0, 0, 0);  \
                accO[0][1] = MFMA16(vR[ks * 2 + 1], pf0, accO[0][1], 0, 0, 0);  \
                accS[0]    = MFMA16(ones4,          pf0, accS[0],    0, 0, 0);  \
                accO[1][0] = MFMA16(vR[ks * 2],     pf1, accO[1][0], 0, 0, 0);  \
                accO[1][1] = MFMA16(vR[ks * 2 + 1], pf1, accO[1][1], 0, 0, 0);  \
                accS[1]    = MFMA16(ones4,          pf1, accS[1],    0, 0, 0);  \
            }                                                                   \
            sc[0][ks] = c0;                                                     \
            sc[1][ks] = c1;                                                     \
        }                                                                       \
        __builtin_amdgcn_s_setprio(0);                                          \
    }

    // ---- prologue: K(0) -> kA ----
#pragma unroll
    for (int ks = 0; ks < 4; ++ks) {
        kAh[ks] = *(const bf8_t*)&kHp[ks * 512];
        kAl[ks] = *(const bf8_t*)&kLp[ks * 512];
    }
    kHp += 2048; kLp += 2048;                          // -> K(1)

    TILE(1, 0, kAh, kAl, kBh, kBl)                     // tile 0: scores only
    kHp += 2048; kLp += 2048;                          // -> K(2); vFp at V(0)

    for (int i = 0; i < 7; ++i) {
        TILE(1, 1, kBh, kBl, kAh, kAl)                 // tile 2i+1 (SM for 2i)
        kHp += 2048; kLp += 2048; vFp += 2048;
        TILE(1, 1, kAh, kAl, kBh, kBl)                 // tile 2i+2 (SM for 2i+1)
        kHp += 2048; kLp += 2048; vFp += 2048;
    }
    TILE(0, 1, kBh, kBl, kAh, kAl)                     // tile 15 (SM for 14)
    vFp += 2048;                                       // -> V(15)

    // ---- drain: exp + PV for tile 15 ----
#pragma unroll
    for (int ks = 0; ks < 4; ++ks) {
        vR[ks * 2]     = *(const bf4_t*)&vFp[(ks * 2) * 256];
        vR[ks * 2 + 1] = *(const bf4_t*)&vFp[(ks * 2 + 1) * 256];
    }
#pragma unroll
    for (int ks = 0; ks < 4; ++ks) {
        unsigned e0[4], e1[4];
#pragma unroll
        for (int r = 0; r < 4; ++r) e0[r] = fbits(EXP2F(sc[0][ks][r]));
#pragma unroll
        for (int r = 0; r < 4; ++r) e1[r] = fbits(EXP2F(sc[1][ks][r]));
        union { uint2 u; bf4_t v; } cv0, cv1;
        cv0.u = make_uint2(__builtin_amdgcn_perm(e0[1], e0[0], PSEL),
                           __builtin_amdgcn_perm(e0[3], e0[2], PSEL));
        cv1.u = make_uint2(__builtin_amdgcn_perm(e1[1], e1[0], PSEL),
                           __builtin_amdgcn_perm(e1[3], e1[2], PSEL));
        bf4_t pf0 = cv0.v, pf1 = cv1.v;
        accO[0][0] = MFMA16(vR[ks * 2],     pf0, accO[0][0], 0, 0, 0);
        accO[0][1] = MFMA16(vR[ks * 2 + 1], pf0, accO[0][1], 0, 0, 0);
        accS[0]    = MFMA16(ones4,          pf0, accS[0],    0, 0, 0);
        accO[1][0] = MFMA16(vR[ks * 2],     pf1, accO[1][0], 0, 0, 0);
        accO[1][1] = MFMA16(vR[ks * 2 + 1], pf1, accO[1][1], 0, 0, 0);
        accS[1]    = MFMA16(ones4,          pf1, accS[1],    0, 0, 0);
    }
#undef TILE

    // ---- epilogue ----
#pragma unroll
    for (int qs = 0; qs < 2; ++qs) {
        float inv = 1.0f / accS[qs][0];
        int s = woff + qs * 16 + l15;
        float* op = out + ((size_t)b * 1024 + s) * 256 + h * 32;
#pragma unroll
        for (int dvs = 0; dvs < 2; ++dvs) {
            float4 o4 = make_float4(accO[qs][dvs][0] * inv, accO[qs][dvs][1] * inv,
                                    accO[qs][dvs][2] * inv, accO[qs][dvs][3] * inv);
            *(float4*)&op[dvs * 16 + quad * 4] = o4;
        }
    }
}

// ---------------------------------------------------------------------------
extern "C" void kernel_launch(void* const* d_in, const int* in_sizes, int n_in,
                              void* d_out, int out_size, void* d_ws, size_t ws_size,
                              hipStream_t stream)
{
    const float* query = (const float*)d_in[0];
    const float* key   = (const float*)d_in[1];
    const float* value = (const float*)d_in[2];
    const float* mask  = (const float*)d_in[3];
    const float* Wq    = (const float*)d_in[4];
    const float* Wk    = (const float*)d_in[5];
    const float* Wv    = (const float*)d_in[6];
    float* out = (float*)d_out;

    const size_t per = (size_t)B_ * H_ * S_ * DK_;
    short* qpH = (short*)d_ws;
    short* qpL = qpH + per;
    short* kpH = qpL + per;
    short* kpL = kpH + per;
    short* vpF = kpL + per;
    short* WpH = vpF + per;
    short* WpL = WpH + 3 * 256 * 256;

    prep_w<<<dim3(24, 4), 256, 0, stream>>>(Wq, Wk, Wv, WpH, WpL);
    proj_kernel<<<dim3(512, 3), 256, 0, stream>>>(query, key, value, mask, WpH, WpL,
                                                  qpH, qpL, kpH, kpL, vpF);
    attn_kernel<<<dim3(8, H_, B_), 256, 0, stream>>>(qpH, qpL, kpH, kpL, vpF, out);
}